// Round 12
// baseline (197.125 us; speedup 1.0000x reference)
//
#include <hip/hip_runtime.h>
#include <math.h>

// Problem constants (from reference)
constexpr int B_ = 8;
constexpr int N_ = 8192;
constexpr int K_ = 48;
constexpr int NFREQ = 8;    // NUM_POS/2
constexpr int NEDGE = 16;
constexpr int FANIN = 23;   // NUM_POS + 7
constexpr float EPSF = 1e-12f;
constexpr int DRANGE = 2 * N_ - 1;  // 16383 possible d = j-n values, offset N_-1

// ---------------- helpers ----------------
struct F3 { float x, y, z; };
__device__ inline F3 f3(float a, float b, float c) { F3 r{a,b,c}; return r; }
__device__ inline F3 sub3(F3 a, F3 b) { return f3(a.x-b.x, a.y-b.y, a.z-b.z); }
__device__ inline F3 cross3(F3 a, F3 b) {
    return f3(a.y*b.z - a.z*b.y, a.z*b.x - a.x*b.z, a.x*b.y - a.y*b.x);
}
__device__ inline F3 norm3(F3 a) {
    float n = sqrtf(a.x*a.x + a.y*a.y + a.z*a.z);
    float inv = 1.0f / fmaxf(n, EPSF);
    return f3(a.x*inv, a.y*inv, a.z*inv);
}
__device__ inline float signf0(float x) {
    return (x > 0.0f) ? 1.0f : ((x < 0.0f) ? -1.0f : 0.0f);
}
__device__ inline unsigned int bf16rne(float x) {
    unsigned int u = __float_as_uint(x);
    return (u + 0x7fffu + ((u >> 16) & 1u)) >> 16;
}
// unpack 8 bf16 (one uint4) -> 8 floats (elem 0 = low 16 bits of x)
__device__ inline void unpack8(uint4 v, float* f) {
    f[0] = __uint_as_float(v.x << 16); f[1] = __uint_as_float(v.x & 0xffff0000u);
    f[2] = __uint_as_float(v.y << 16); f[3] = __uint_as_float(v.y & 0xffff0000u);
    f[4] = __uint_as_float(v.z << 16); f[5] = __uint_as_float(v.z & 0xffff0000u);
    f[6] = __uint_as_float(v.w << 16); f[7] = __uint_as_float(v.w & 0xffff0000u);
}

// ---------------- kernel 1: positional-encoding table (bf16, 32B rows) ----------------
__global__ void build_table(const float* __restrict__ tfrq, const float* __restrict__ ts,
                            const float* __restrict__ W, const float* __restrict__ bias,
                            unsigned short* __restrict__ T) {
    int idx = blockIdx.x * blockDim.x + threadIdx.x;
    if (idx >= DRANGE) return;
    float d = (float)(idx - (N_ - 1));
    float h[NEDGE];
    #pragma unroll
    for (int o = 0; o < NEDGE; o++) h[o] = bias[o];
    float tscale = ts[0];
    for (int f = 0; f < NFREQ; f++) {
        float s, c;
        sincosf(d * (tfrq[f] * tscale), &s, &c);
        #pragma unroll
        for (int o = 0; o < NEDGE; o++)
            h[o] = fmaf(s, W[o * FANIN + f], fmaf(c, W[o * FANIN + NFREQ + f], h[o]));
    }
    uint4 r0, r1;
    r0.x = bf16rne(h[0])  | (bf16rne(h[1])  << 16);
    r0.y = bf16rne(h[2])  | (bf16rne(h[3])  << 16);
    r0.z = bf16rne(h[4])  | (bf16rne(h[5])  << 16);
    r0.w = bf16rne(h[6])  | (bf16rne(h[7])  << 16);
    r1.x = bf16rne(h[8])  | (bf16rne(h[9])  << 16);
    r1.y = bf16rne(h[10]) | (bf16rne(h[11]) << 16);
    r1.z = bf16rne(h[12]) | (bf16rne(h[13]) << 16);
    r1.w = bf16rne(h[14]) | (bf16rne(h[15]) << 16);
    uint4* Tp = (uint4*)(T + (size_t)idx * 16);
    Tp[0] = r0; Tp[1] = r1;
}

// ---------------- kernel 2: per-node frame (12 floats packed, 64B stride) ----------------
__global__ void compute_F(const float* __restrict__ X, float* __restrict__ F) {
    int idx = blockIdx.x * blockDim.x + threadIdx.x;
    if (idx >= B_ * N_) return;
    int n = idx & (N_ - 1);
    const float* Xp = X + (size_t)idx * 3;
    float o[12];
    o[0] = Xp[0]; o[1] = Xp[1]; o[2] = Xp[2];
    #pragma unroll
    for (int i = 3; i < 12; i++) o[i] = 0.0f;
    if (n != 0 && n < N_ - 2) {
        F3 xm = f3(Xp[-3], Xp[-2], Xp[-1]);
        F3 x0 = f3(Xp[0], Xp[1], Xp[2]);
        F3 xp = f3(Xp[3], Xp[4], Xp[5]);
        F3 u2 = norm3(sub3(x0, xm));
        F3 u1 = norm3(sub3(xp, x0));
        F3 n2 = norm3(cross3(u2, u1));
        F3 o1 = norm3(sub3(u2, u1));
        F3 cc = cross3(o1, n2);
        o[3] = o1.x; o[4] = o1.y; o[5] = o1.z;
        o[6] = n2.x; o[7] = n2.y; o[8] = n2.z;
        o[9] = cc.x; o[10] = cc.y; o[11] = cc.z;
    }
    float4* Fp = (float4*)(F + (size_t)idx * 16);
    Fp[0] = make_float4(o[0], o[1], o[2], o[3]);
    Fp[1] = make_float4(o[4], o[5], o[6], o[7]);
    Fp[2] = make_float4(o[8], o[9], o[10], o[11]);
}

// ---------------- core per-edge computation (ARITHMETIC UNCHANGED since R4) ----------------
// Operands passed in registers (fetched cooperatively by caller).
__device__ inline void compute_edge_regs(float4 a0, float4 a1, float4 a2,
                                         float4 b0, float4 b1, float4 b2,
                                         uint4 t0, uint4 t1,
                                         const float (*sWq)[8],
                                         float* __restrict__ h) {
    float tv[16];
    unpack8(t0, tv);
    unpack8(t1, tv + 8);

    float A1x = a0.w, A1y = a1.x, A1z = a1.y;
    float A2x = a1.z, A2y = a1.w, A2z = a2.x;
    float A3x = a2.y, A3y = a2.z, A3z = a2.w;
    float B1x = b0.w, B1y = b1.x, B1z = b1.y;
    float B2x = b1.z, B2y = b1.w, B2z = b2.x;
    float B3x = b2.y, B3y = b2.z, B3z = b2.w;

    float dX0 = b0.x - a0.x, dX1 = b0.y - a0.y, dX2 = b0.z - a0.z;
    float v0 = A1x*dX0 + A1y*dX1 + A1z*dX2;
    float v1 = A2x*dX0 + A2y*dX1 + A2z*dX2;
    float v2 = A3x*dX0 + A3y*dX1 + A3z*dX2;
    float vinv = 1.0f / fmaxf(sqrtf(v0*v0 + v1*v1 + v2*v2), EPSF);
    float dU0 = v0*vinv, dU1 = v1*vinv, dU2 = v2*vinv;

    float R00 = A1x*B1x + A2x*B2x + A3x*B3x;
    float R11 = A1y*B1y + A2y*B2y + A3y*B3y;
    float R22 = A1z*B1z + A2z*B2z + A3z*B3z;
    float R21 = A1z*B1y + A2z*B2y + A3z*B3y;
    float R12 = A1y*B1z + A2y*B2z + A3y*B3z;
    float R02 = A1x*B1z + A2x*B2z + A3x*B3z;
    float R20 = A1z*B1x + A2z*B2x + A3z*B3x;
    float R10 = A1y*B1x + A2y*B2x + A3y*B3x;
    float R01 = A1x*B1y + A2x*B2y + A3x*B3y;

    float mg0 = 0.5f * sqrtf(fabsf(1.0f + R00 - R11 - R22) + EPSF);
    float mg1 = 0.5f * sqrtf(fabsf(1.0f - R00 + R11 - R22) + EPSF);
    float mg2 = 0.5f * sqrtf(fabsf(1.0f - R00 - R11 + R22) + EPSF);
    float qx = signf0(R21 - R12) * mg0;
    float qy = signf0(R02 - R20) * mg1;
    float qz = signf0(R10 - R01) * mg2;
    float qw = 0.5f * sqrtf(fmaxf(1.0f + R00 + R11 + R22, 0.0f) + EPSF);
    float qinv = 1.0f / fmaxf(sqrtf(qx*qx + qy*qy + qz*qz + qw*qw), EPSF);
    qx *= qinv; qy *= qinv; qz *= qinv; qw *= qinv;

    float q[7] = {dU0, dU1, dU2, qx, qy, qz, qw};
    #pragma unroll
    for (int o = 0; o < NEDGE; o++) {
        float a = tv[o];
        #pragma unroll
        for (int f = 0; f < 7; f++) a = fmaf(q[f], sWq[o][f], a);
        h[o] = a;
    }
}

// ---------------- edge pass: wave = 4n x 16k, cooperative gathers + 1KB stores ----------------
// grid = 8(b) x 3(kg) x 128(nt of 64 n) = 3072 blocks. b in low 3 bits (XCD pin).
// TA-request ledger/edge: fj 1 (coop, 4 lanes/line) + T 1 (coop, 2 lanes/line)
//   + store 1 (transposed) + fn 0.19 (broadcast) + E 0.06 = 3.25  (was 6.25).
// One wave-private LDS buffer time-multiplexed: fj stage -> T stage -> h transpose.
// DS ops are in-order within a wave (same guarantee the R6+ h-transpose relies on).
__launch_bounds__(256)
__global__ void edge_pass(const int* __restrict__ E, const float* __restrict__ F,
                          const unsigned short* __restrict__ T, const float* __restrict__ Wfull,
                          float* __restrict__ acc, float* __restrict__ out) {
    int bid = blockIdx.x;
    int b = bid & 7;
    int r = bid >> 3;
    int kg = r % 3;             // k-group of 16
    int nt = r / 3;             // 0..127
    int tid = threadIdx.x;
    int w = tid >> 6, l = tid & 63;
    int nn = l >> 4, kk = l & 15;
    int k = kg * 16 + kk;

    __shared__ float sBuf[4][64 * 17];     // wave-private staging (pad 17)
    __shared__ int   sJ[4][64];
    __shared__ float sWq[NEDGE][8];
    __shared__ float sAcc[4][16][NEDGE];

    if (tid < NEDGE * 8) {
        int o = tid >> 3, f = tid & 7;
        sWq[o][f] = (f < 7) ? Wfull[o * FANIN + 16 + f] : 0.0f;
    }
    __syncthreads();

    size_t bbase = (size_t)b * N_;
    int nbase = nt * 64;
    float* buf = sBuf[w];
    int* js = sJ[w];

    float vsq[NEDGE];
    #pragma unroll
    for (int o = 0; o < NEDGE; o++) vsq[o] = 0.0f;

    for (int it = 0; it < 4; it++) {
        int rowbase = nbase + it * 16 + w * 4;   // first of this wave-iter's 4 n-rows
        int n = rowbase + nn;
        size_t node = bbase + n;

        // own fn: 16 lanes share n -> broadcast-merged (3 req / 16 edges)
        const float4* fnp = (const float4*)(F + node * 16);
        float4 a0 = fnp[0], a1 = fnp[1], a2 = fnp[2];

        int j = E[node * K_ + k];
        js[l] = j;                                // redistribute j via LDS

        // --- cooperative fj gather: lane l loads quarter (l&3) of edge (l>>2)+16s ---
        float4 fjq[4];
        #pragma unroll
        for (int s = 0; s < 4; s++) {
            int e = (l >> 2) + 16 * s;
            int je = js[e];
            const float4* fp = (const float4*)(F + (bbase + (size_t)je) * 16);
            fjq[s] = fp[l & 3];                   // 16 distinct lines / instr
        }
        #pragma unroll
        for (int s = 0; s < 4; s++) {
            int e = (l >> 2) + 16 * s;
            *(float4*)(buf + e * 17 + (l & 3) * 4) = fjq[s];
        }
        float4 b0 = *(float4*)(buf + l * 17 + 0);
        float4 b1 = *(float4*)(buf + l * 17 + 4);
        float4 b2 = *(float4*)(buf + l * 17 + 8);

        // --- cooperative T gather: lane l loads half (l&1) of edge (l>>1)+32s ---
        uint4 tq[2];
        #pragma unroll
        for (int s = 0; s < 2; s++) {
            int e = (l >> 1) + 32 * s;
            int je = js[e];
            int ne = rowbase + (e >> 4);
            const uint4* tp = (const uint4*)(T + (size_t)(je - ne + (N_ - 1)) * 16);
            tq[s] = tp[l & 1];                    // 32 distinct lines / instr
        }
        #pragma unroll
        for (int s = 0; s < 2; s++) {
            int e = (l >> 1) + 32 * s;
            *(uint4*)(buf + e * 17 + (l & 1) * 4) = tq[s];
        }
        uint4 t0 = *(uint4*)(buf + l * 17 + 0);
        uint4 t1 = *(uint4*)(buf + l * 17 + 4);

        float h[NEDGE];
        compute_edge_regs(a0, a1, a2, b0, b1, b2, t0, t1, sWq, h);

        #pragma unroll
        for (int o = 0; o < NEDGE; o++) vsq[o] = fmaf(h[o], h[o], vsq[o]);

        // --- h transpose through the same buffer ---
        #pragma unroll
        for (int q = 0; q < 4; q++)
            *(float4*)(buf + l * 17 + q * 4) =
                make_float4(h[4*q], h[4*q+1], h[4*q+2], h[4*q+3]);

        // store: instr s writes n-row s's 16 edges = contiguous 1KB, uniform base
        #pragma unroll
        for (int s = 0; s < 4; s++) {
            int n_s = rowbase + s;
            float4 v = *(float4*)(buf + ((s << 4) + (l >> 2)) * 17 + (l & 3) * 4);
            size_t outb = ((bbase + n_s) * K_ + (size_t)kg * 16) * 16;
            *(float4*)(out + outb + l * 4) = v;
        }
    }

    // ssq: reduce over the 4 n-subrows within the wave (lane bits 4-5)
    #pragma unroll
    for (int o = 0; o < NEDGE; o++) {
        float v = vsq[o];
        v += __shfl_xor(v, 16, 64);
        v += __shfl_xor(v, 32, 64);
        vsq[o] = v;
    }
    if (nn == 0 && l < 16) {
        #pragma unroll
        for (int o = 0; o < NEDGE; o++) sAcc[w][kk][o] = vsq[o];
    }
    __syncthreads();
    {
        int kk2 = tid >> 4, o = tid & 15;
        float t = sAcc[0][kk2][o] + sAcc[1][kk2][o] + sAcc[2][kk2][o] + sAcc[3][kk2][o];
        atomicAdd(&acc[((size_t)b * K_ + kg * 16 + kk2) * NEDGE + o], t);
    }
}

// ---------------- reciprocal norms ----------------
__global__ void inv_kernel(const float* __restrict__ acc, float* __restrict__ rinv) {
    int i = blockIdx.x * blockDim.x + threadIdx.x;
    if (i >= B_ * K_ * NEDGE) return;
    rinv[i] = 1.0f / fmaxf(sqrtf(acc[i]), EPSF);
}

// ---------------- rescale pass (streaming RMW; re-read is L3-resident) ----------------
// R11 lesson: bf16-staging alternative measured 20us SLOWER end-to-end. Keep RMW.
__launch_bounds__(256)
__global__ void scale_kernel(float* __restrict__ out, const float* __restrict__ rinv) {
    size_t idx = (size_t)blockIdx.x * blockDim.x + threadIdx.x;  // float4 index
    constexpr size_t TOTAL4 = (size_t)B_ * N_ * K_ * 4;
    if (idx >= TOTAL4) return;
    size_t e0 = idx * 4;
    unsigned int o0 = (unsigned int)(e0 & 15);
    unsigned int key = (unsigned int)(e0 >> 4);       // (b*N+n)*K + k
    unsigned int k = key % (unsigned int)K_;
    unsigned int b = key / (unsigned int)(N_ * K_);
    const float* rp = rinv + ((size_t)b * K_ + k) * 16 + o0;
    float4 vv = *reinterpret_cast<float4*>(out + e0);
    vv.x *= rp[0]; vv.y *= rp[1]; vv.z *= rp[2]; vv.w *= rp[3];
    *reinterpret_cast<float4*>(out + e0) = vv;
}

// ---------------- launch ----------------
extern "C" void kernel_launch(void* const* d_in, const int* in_sizes, int n_in,
                              void* d_out, int out_size, void* d_ws, size_t ws_size,
                              hipStream_t stream) {
    const float* X    = (const float*)d_in[0];   // p (B,N,3)
    const int*   E    = (const int*)d_in[1];     // e_idx (B,N,K)
    // d_in[2] = mask (unused by reference)
    const float* tfrq = (const float*)d_in[3];   // (8,)
    const float* ts   = (const float*)d_in[4];   // scalar
    const float* W    = (const float*)d_in[5];   // (16,23)
    const float* bias = (const float*)d_in[6];   // (16,)
    float* out = (float*)d_out;

    float* F = (float*)d_ws;                                          // 8*8192*16 f32 = 4.19 MB
    unsigned short* T = (unsigned short*)(F + (size_t)B_ * N_ * 16);  // 16383*16 bf16 = 524 KB
    float* acc  = (float*)(T + (size_t)DRANGE * 16);                  // 6144 f32
    float* rinv = acc + B_ * K_ * NEDGE;                              // 6144 f32

    (void)hipMemsetAsync(acc, 0, (size_t)B_ * K_ * NEDGE * sizeof(float), stream);

    build_table<<<(DRANGE + 255) / 256, 256, 0, stream>>>(tfrq, ts, W, bias, T);
    compute_F<<<(B_ * N_ + 255) / 256, 256, 0, stream>>>(X, F);

    int grid = 8 * 3 * 128;   // 3072 blocks, b in low 3 bits
    edge_pass<<<grid, 256, 0, stream>>>(E, F, T, W, acc, out);

    inv_kernel<<<(B_ * K_ * NEDGE + 255) / 256, 256, 0, stream>>>(acc, rinv);

    constexpr size_t TOTAL4 = (size_t)B_ * N_ * K_ * 4;
    scale_kernel<<<(TOTAL4 + 255) / 256, 256, 0, stream>>>(out, rinv);
}

// Round 13
// 144.166 us; speedup vs baseline: 1.3673x; 1.3673x over previous
//
#include <hip/hip_runtime.h>
#include <math.h>

// Problem constants (from reference)
constexpr int B_ = 8;
constexpr int N_ = 8192;
constexpr int K_ = 48;
constexpr int NFREQ = 8;    // NUM_POS/2
constexpr int NEDGE = 16;
constexpr int FANIN = 23;   // NUM_POS + 7
constexpr float EPSF = 1e-12f;
constexpr int DRANGE = 2 * N_ - 1;  // 16383 possible d = j-n values, offset N_-1
constexpr int DPAD = 16384;         // padded table slot count for fused prep kernel

// ---------------- helpers ----------------
struct F3 { float x, y, z; };
__device__ inline F3 f3(float a, float b, float c) { F3 r{a,b,c}; return r; }
__device__ inline F3 sub3(F3 a, F3 b) { return f3(a.x-b.x, a.y-b.y, a.z-b.z); }
__device__ inline F3 cross3(F3 a, F3 b) {
    return f3(a.y*b.z - a.z*b.y, a.z*b.x - a.x*b.z, a.x*b.y - a.y*b.x);
}
__device__ inline F3 norm3(F3 a) {
    float n = sqrtf(a.x*a.x + a.y*a.y + a.z*a.z);
    float inv = 1.0f / fmaxf(n, EPSF);
    return f3(a.x*inv, a.y*inv, a.z*inv);
}
__device__ inline float signf0(float x) {
    return (x > 0.0f) ? 1.0f : ((x < 0.0f) ? -1.0f : 0.0f);
}
__device__ inline unsigned int bf16rne(float x) {
    unsigned int u = __float_as_uint(x);
    return (u + 0x7fffu + ((u >> 16) & 1u)) >> 16;
}
// unpack 8 bf16 (one uint4) -> 8 floats (elem 0 = low 16 bits of x)
__device__ inline void unpack8(uint4 v, float* f) {
    f[0] = __uint_as_float(v.x << 16); f[1] = __uint_as_float(v.x & 0xffff0000u);
    f[2] = __uint_as_float(v.y << 16); f[3] = __uint_as_float(v.y & 0xffff0000u);
    f[4] = __uint_as_float(v.z << 16); f[5] = __uint_as_float(v.z & 0xffff0000u);
    f[6] = __uint_as_float(v.w << 16); f[7] = __uint_as_float(v.w & 0xffff0000u);
}

// ---------------- fused prep: PE table (bf16) + per-node frames ----------------
// flat id < DPAD        : table row (DRANGE used)
// flat id in [DPAD, ..) : frame row (B*N rows)
__global__ void prep_kernel(const float* __restrict__ X,
                            const float* __restrict__ tfrq, const float* __restrict__ ts,
                            const float* __restrict__ W, const float* __restrict__ bias,
                            unsigned short* __restrict__ T, float* __restrict__ F) {
    int idx = blockIdx.x * blockDim.x + threadIdx.x;
    if (idx < DPAD) {
        if (idx >= DRANGE) return;
        float d = (float)(idx - (N_ - 1));
        float h[NEDGE];
        #pragma unroll
        for (int o = 0; o < NEDGE; o++) h[o] = bias[o];
        float tscale = ts[0];
        for (int f = 0; f < NFREQ; f++) {
            float s, c;
            sincosf(d * (tfrq[f] * tscale), &s, &c);
            #pragma unroll
            for (int o = 0; o < NEDGE; o++)
                h[o] = fmaf(s, W[o * FANIN + f], fmaf(c, W[o * FANIN + NFREQ + f], h[o]));
        }
        uint4 r0, r1;
        r0.x = bf16rne(h[0])  | (bf16rne(h[1])  << 16);
        r0.y = bf16rne(h[2])  | (bf16rne(h[3])  << 16);
        r0.z = bf16rne(h[4])  | (bf16rne(h[5])  << 16);
        r0.w = bf16rne(h[6])  | (bf16rne(h[7])  << 16);
        r1.x = bf16rne(h[8])  | (bf16rne(h[9])  << 16);
        r1.y = bf16rne(h[10]) | (bf16rne(h[11]) << 16);
        r1.z = bf16rne(h[12]) | (bf16rne(h[13]) << 16);
        r1.w = bf16rne(h[14]) | (bf16rne(h[15]) << 16);
        uint4* Tp = (uint4*)(T + (size_t)idx * 16);
        Tp[0] = r0; Tp[1] = r1;
        return;
    }
    int fid = idx - DPAD;
    if (fid >= B_ * N_) return;
    int n = fid & (N_ - 1);
    const float* Xp = X + (size_t)fid * 3;
    float o[12];
    o[0] = Xp[0]; o[1] = Xp[1]; o[2] = Xp[2];
    #pragma unroll
    for (int i = 3; i < 12; i++) o[i] = 0.0f;
    if (n != 0 && n < N_ - 2) {
        F3 xm = f3(Xp[-3], Xp[-2], Xp[-1]);
        F3 x0 = f3(Xp[0], Xp[1], Xp[2]);
        F3 xp = f3(Xp[3], Xp[4], Xp[5]);
        F3 u2 = norm3(sub3(x0, xm));
        F3 u1 = norm3(sub3(xp, x0));
        F3 n2 = norm3(cross3(u2, u1));
        F3 o1 = norm3(sub3(u2, u1));
        F3 cc = cross3(o1, n2);
        o[3] = o1.x; o[4] = o1.y; o[5] = o1.z;
        o[6] = n2.x; o[7] = n2.y; o[8] = n2.z;
        o[9] = cc.x; o[10] = cc.y; o[11] = cc.z;
    }
    float4* Fp = (float4*)(F + (size_t)fid * 16);
    Fp[0] = make_float4(o[0], o[1], o[2], o[3]);
    Fp[1] = make_float4(o[4], o[5], o[6], o[7]);
    Fp[2] = make_float4(o[8], o[9], o[10], o[11]);
}

// ---------------- core per-edge computation (ARITHMETIC UNCHANGED since R4) ----------------
__device__ inline void compute_edge(float4 a0, float4 a1, float4 a2,
                                    const float* __restrict__ F,
                                    const unsigned short* __restrict__ T,
                                    const float (*sWq)[8],
                                    size_t bbase, int n, int j,
                                    float* __restrict__ h) {
    const float4* fjp = (const float4*)(F + (bbase + (size_t)j) * 16);
    float4 b0 = fjp[0], b1 = fjp[1], b2 = fjp[2];
    const uint4* tp = (const uint4*)(T + (size_t)(j - n + (N_ - 1)) * 16);
    uint4 t0 = tp[0], t1 = tp[1];
    float tv[16];
    unpack8(t0, tv);
    unpack8(t1, tv + 8);

    float A1x = a0.w, A1y = a1.x, A1z = a1.y;
    float A2x = a1.z, A2y = a1.w, A2z = a2.x;
    float A3x = a2.y, A3y = a2.z, A3z = a2.w;
    float B1x = b0.w, B1y = b1.x, B1z = b1.y;
    float B2x = b1.z, B2y = b1.w, B2z = b2.x;
    float B3x = b2.y, B3y = b2.z, B3z = b2.w;

    float dX0 = b0.x - a0.x, dX1 = b0.y - a0.y, dX2 = b0.z - a0.z;
    float v0 = A1x*dX0 + A1y*dX1 + A1z*dX2;
    float v1 = A2x*dX0 + A2y*dX1 + A2z*dX2;
    float v2 = A3x*dX0 + A3y*dX1 + A3z*dX2;
    float vinv = 1.0f / fmaxf(sqrtf(v0*v0 + v1*v1 + v2*v2), EPSF);
    float dU0 = v0*vinv, dU1 = v1*vinv, dU2 = v2*vinv;

    float R00 = A1x*B1x + A2x*B2x + A3x*B3x;
    float R11 = A1y*B1y + A2y*B2y + A3y*B3y;
    float R22 = A1z*B1z + A2z*B2z + A3z*B3z;
    float R21 = A1z*B1y + A2z*B2y + A3z*B3y;
    float R12 = A1y*B1z + A2y*B2z + A3y*B3z;
    float R02 = A1x*B1z + A2x*B2z + A3x*B3z;
    float R20 = A1z*B1x + A2z*B2x + A3z*B3x;
    float R10 = A1y*B1x + A2y*B2x + A3y*B3x;
    float R01 = A1x*B1y + A2x*B2y + A3x*B3y;

    float mg0 = 0.5f * sqrtf(fabsf(1.0f + R00 - R11 - R22) + EPSF);
    float mg1 = 0.5f * sqrtf(fabsf(1.0f - R00 + R11 - R22) + EPSF);
    float mg2 = 0.5f * sqrtf(fabsf(1.0f - R00 - R11 + R22) + EPSF);
    float qx = signf0(R21 - R12) * mg0;
    float qy = signf0(R02 - R20) * mg1;
    float qz = signf0(R10 - R01) * mg2;
    float qw = 0.5f * sqrtf(fmaxf(1.0f + R00 + R11 + R22, 0.0f) + EPSF);
    float qinv = 1.0f / fmaxf(sqrtf(qx*qx + qy*qy + qz*qz + qw*qw), EPSF);
    qx *= qinv; qy *= qinv; qz *= qinv; qw *= qinv;

    float q[7] = {dU0, dU1, dU2, qx, qy, qz, qw};
    #pragma unroll
    for (int o = 0; o < NEDGE; o++) {
        float a = tv[o];
        #pragma unroll
        for (int f = 0; f < 7; f++) a = fmaf(q[f], sWq[o][f], a);
        h[o] = a;
    }
}

// ---------------- edge pass: wave = 4n x 16k, contiguous 1KB stores (R7 = best known) ----------------
// grid = 8(b) x 3(kg) x 128(nt of 64 n) = 3072 blocks. b in low 3 bits (XCD pin).
// R12 lesson: cooperative LDS-staged gathers (fj/T) regress — +48 VGPR, occupancy
// 21%, serial E->LDS->gather chain. Direct per-lane gathers + store-transpose only.
__launch_bounds__(256)
__global__ void edge_pass(const int* __restrict__ E, const float* __restrict__ F,
                          const unsigned short* __restrict__ T, const float* __restrict__ Wfull,
                          float* __restrict__ acc, float* __restrict__ out) {
    int bid = blockIdx.x;
    int b = bid & 7;
    int r = bid >> 3;
    int kg = r % 3;             // k-group of 16
    int nt = r / 3;             // 0..127
    int tid = threadIdx.x;
    int w = tid >> 6, l = tid & 63;
    int nn = l >> 4, kk = l & 15;
    int k = kg * 16 + kk;

    __shared__ float sT[4][64 * 17];       // wave-private transpose buffers (pad 17)
    __shared__ float sWq[NEDGE][8];
    __shared__ float sAcc[4][16][NEDGE];

    if (tid < NEDGE * 8) {
        int o = tid >> 3, f = tid & 7;
        sWq[o][f] = (f < 7) ? Wfull[o * FANIN + 16 + f] : 0.0f;
    }
    __syncthreads();

    size_t bbase = (size_t)b * N_;
    int nbase = nt * 64;
    float* myT = sT[w];

    float vsq[NEDGE];
    #pragma unroll
    for (int o = 0; o < NEDGE; o++) vsq[o] = 0.0f;

    for (int it = 0; it < 4; it++) {
        int n = nbase + it * 16 + w * 4 + nn;
        size_t node = bbase + n;
        const float4* fnp = (const float4*)(F + node * 16);
        float4 a0 = fnp[0], a1 = fnp[1], a2 = fnp[2];
        int j = E[node * K_ + k];

        float h[NEDGE];
        compute_edge(a0, a1, a2, F, T, sWq, bbase, n, j, h);

        #pragma unroll
        for (int o = 0; o < NEDGE; o++) vsq[o] = fmaf(h[o], h[o], vsq[o]);

        // wave-private LDS transpose (lockstep wave -> no __syncthreads)
        #pragma unroll
        for (int q = 0; q < 4; q++)
            *(float4*)(myT + l * 17 + q * 4) =
                make_float4(h[4*q], h[4*q+1], h[4*q+2], h[4*q+3]);

        // store: instr s writes n-row s's 16 edges = contiguous 1KB, uniform base
        #pragma unroll
        for (int s = 0; s < 4; s++) {
            int n_s = nbase + it * 16 + w * 4 + s;
            float4 v = *(float4*)(myT + ((s << 4) + (l >> 2)) * 17 + (l & 3) * 4);
            size_t outb = ((bbase + n_s) * K_ + (size_t)kg * 16) * 16;
            *(float4*)(out + outb + l * 4) = v;
        }
    }

    // ssq: reduce over the 4 n-subrows within the wave (lane bits 4-5)
    #pragma unroll
    for (int o = 0; o < NEDGE; o++) {
        float v = vsq[o];
        v += __shfl_xor(v, 16, 64);
        v += __shfl_xor(v, 32, 64);
        vsq[o] = v;
    }
    if (nn == 0 && l < 16) {
        #pragma unroll
        for (int o = 0; o < NEDGE; o++) sAcc[w][kk][o] = vsq[o];
    }
    __syncthreads();
    {
        int kk2 = tid >> 4, o = tid & 15;
        float t = sAcc[0][kk2][o] + sAcc[1][kk2][o] + sAcc[2][kk2][o] + sAcc[3][kk2][o];
        atomicAdd(&acc[((size_t)b * K_ + kg * 16 + kk2) * NEDGE + o], t);
    }
}

// ---------------- reciprocal norms ----------------
__global__ void inv_kernel(const float* __restrict__ acc, float* __restrict__ rinv) {
    int i = blockIdx.x * blockDim.x + threadIdx.x;
    if (i >= B_ * K_ * NEDGE) return;
    rinv[i] = 1.0f / fmaxf(sqrtf(acc[i]), EPSF);
}

// ---------------- rescale pass (streaming RMW; re-read is L3-resident) ----------------
// R11 lesson: bf16-staging alternative is 20us slower end-to-end; R10: nontemporal
// stores cause partial-sector write amplification. Plain f32 RMW is best.
__launch_bounds__(256)
__global__ void scale_kernel(float* __restrict__ out, const float* __restrict__ rinv) {
    size_t idx = (size_t)blockIdx.x * blockDim.x + threadIdx.x;  // float4 index
    constexpr size_t TOTAL4 = (size_t)B_ * N_ * K_ * 4;
    if (idx >= TOTAL4) return;
    size_t e0 = idx * 4;
    unsigned int o0 = (unsigned int)(e0 & 15);
    unsigned int key = (unsigned int)(e0 >> 4);       // (b*N+n)*K + k
    unsigned int k = key % (unsigned int)K_;
    unsigned int b = key / (unsigned int)(N_ * K_);
    float4 rv = *(const float4*)(rinv + ((size_t)b * K_ + k) * 16 + o0);  // one 16B load
    float4 vv = *reinterpret_cast<float4*>(out + e0);
    vv.x *= rv.x; vv.y *= rv.y; vv.z *= rv.z; vv.w *= rv.w;
    *reinterpret_cast<float4*>(out + e0) = vv;
}

// ---------------- launch ----------------
extern "C" void kernel_launch(void* const* d_in, const int* in_sizes, int n_in,
                              void* d_out, int out_size, void* d_ws, size_t ws_size,
                              hipStream_t stream) {
    const float* X    = (const float*)d_in[0];   // p (B,N,3)
    const int*   E    = (const int*)d_in[1];     // e_idx (B,N,K)
    // d_in[2] = mask (unused by reference)
    const float* tfrq = (const float*)d_in[3];   // (8,)
    const float* ts   = (const float*)d_in[4];   // scalar
    const float* W    = (const float*)d_in[5];   // (16,23)
    const float* bias = (const float*)d_in[6];   // (16,)
    float* out = (float*)d_out;

    float* F = (float*)d_ws;                                          // 8*8192*16 f32 = 4.19 MB
    unsigned short* T = (unsigned short*)(F + (size_t)B_ * N_ * 16);  // 16383*16 bf16 = 524 KB
    float* acc  = (float*)(T + (size_t)DRANGE * 16);                  // 6144 f32
    float* rinv = acc + B_ * K_ * NEDGE;                              // 6144 f32

    (void)hipMemsetAsync(acc, 0, (size_t)B_ * K_ * NEDGE * sizeof(float), stream);

    int prep_threads = DPAD + B_ * N_;
    prep_kernel<<<(prep_threads + 255) / 256, 256, 0, stream>>>(X, tfrq, ts, W, bias, T, F);

    int grid = 8 * 3 * 128;   // 3072 blocks, b in low 3 bits
    edge_pass<<<grid, 256, 0, stream>>>(E, F, T, W, acc, out);

    inv_kernel<<<(B_ * K_ * NEDGE + 255) / 256, 256, 0, stream>>>(acc, rinv);

    constexpr size_t TOTAL4 = (size_t)B_ * N_ * K_ * 4;
    scale_kernel<<<(TOTAL4 + 255) / 256, 256, 0, stream>>>(out, rinv);
}

// Round 14
// 142.217 us; speedup vs baseline: 1.3861x; 1.0137x over previous
//
#include <hip/hip_runtime.h>
#include <math.h>

// Problem constants (from reference)
constexpr int B_ = 8;
constexpr int N_ = 8192;
constexpr int K_ = 48;
constexpr int NFREQ = 8;    // NUM_POS/2
constexpr int NEDGE = 16;
constexpr int FANIN = 23;   // NUM_POS + 7
constexpr float EPSF = 1e-12f;
constexpr int DRANGE = 2 * N_ - 1;  // 16383 possible d = j-n values, offset N_-1
constexpr int DPAD = 16384;         // padded table slot count for fused prep kernel

typedef _Float16 f16x2 __attribute__((ext_vector_type(2)));

// ---------------- helpers ----------------
struct F3 { float x, y, z; };
__device__ inline F3 f3(float a, float b, float c) { F3 r{a,b,c}; return r; }
__device__ inline F3 sub3(F3 a, F3 b) { return f3(a.x-b.x, a.y-b.y, a.z-b.z); }
__device__ inline F3 cross3(F3 a, F3 b) {
    return f3(a.y*b.z - a.z*b.y, a.z*b.x - a.x*b.z, a.x*b.y - a.y*b.x);
}
__device__ inline F3 norm3(F3 a) {
    float n = sqrtf(a.x*a.x + a.y*a.y + a.z*a.z);
    float inv = 1.0f / fmaxf(n, EPSF);
    return f3(a.x*inv, a.y*inv, a.z*inv);
}
__device__ inline float signf0(float x) {
    return (x > 0.0f) ? 1.0f : ((x < 0.0f) ? -1.0f : 0.0f);
}
__device__ inline unsigned int bf16rne(float x) {
    unsigned int u = __float_as_uint(x);
    return (u + 0x7fffu + ((u >> 16) & 1u)) >> 16;
}
// unpack 8 bf16 (one uint4) -> 8 floats (elem 0 = low 16 bits of x)
__device__ inline void unpack8(uint4 v, float* f) {
    f[0] = __uint_as_float(v.x << 16); f[1] = __uint_as_float(v.x & 0xffff0000u);
    f[2] = __uint_as_float(v.y << 16); f[3] = __uint_as_float(v.y & 0xffff0000u);
    f[4] = __uint_as_float(v.z << 16); f[5] = __uint_as_float(v.z & 0xffff0000u);
    f[6] = __uint_as_float(v.w << 16); f[7] = __uint_as_float(v.w & 0xffff0000u);
}

// ---------------- fused prep: PE table (bf16) + per-node frames ----------------
__global__ void prep_kernel(const float* __restrict__ X,
                            const float* __restrict__ tfrq, const float* __restrict__ ts,
                            const float* __restrict__ W, const float* __restrict__ bias,
                            unsigned short* __restrict__ T, float* __restrict__ F) {
    int idx = blockIdx.x * blockDim.x + threadIdx.x;
    if (idx < DPAD) {
        if (idx >= DRANGE) return;
        float d = (float)(idx - (N_ - 1));
        float h[NEDGE];
        #pragma unroll
        for (int o = 0; o < NEDGE; o++) h[o] = bias[o];
        float tscale = ts[0];
        for (int f = 0; f < NFREQ; f++) {
            float s, c;
            sincosf(d * (tfrq[f] * tscale), &s, &c);
            #pragma unroll
            for (int o = 0; o < NEDGE; o++)
                h[o] = fmaf(s, W[o * FANIN + f], fmaf(c, W[o * FANIN + NFREQ + f], h[o]));
        }
        uint4 r0, r1;
        r0.x = bf16rne(h[0])  | (bf16rne(h[1])  << 16);
        r0.y = bf16rne(h[2])  | (bf16rne(h[3])  << 16);
        r0.z = bf16rne(h[4])  | (bf16rne(h[5])  << 16);
        r0.w = bf16rne(h[6])  | (bf16rne(h[7])  << 16);
        r1.x = bf16rne(h[8])  | (bf16rne(h[9])  << 16);
        r1.y = bf16rne(h[10]) | (bf16rne(h[11]) << 16);
        r1.z = bf16rne(h[12]) | (bf16rne(h[13]) << 16);
        r1.w = bf16rne(h[14]) | (bf16rne(h[15]) << 16);
        uint4* Tp = (uint4*)(T + (size_t)idx * 16);
        Tp[0] = r0; Tp[1] = r1;
        return;
    }
    int fid = idx - DPAD;
    if (fid >= B_ * N_) return;
    int n = fid & (N_ - 1);
    const float* Xp = X + (size_t)fid * 3;
    float o[12];
    o[0] = Xp[0]; o[1] = Xp[1]; o[2] = Xp[2];
    #pragma unroll
    for (int i = 3; i < 12; i++) o[i] = 0.0f;
    if (n != 0 && n < N_ - 2) {
        F3 xm = f3(Xp[-3], Xp[-2], Xp[-1]);
        F3 x0 = f3(Xp[0], Xp[1], Xp[2]);
        F3 xp = f3(Xp[3], Xp[4], Xp[5]);
        F3 u2 = norm3(sub3(x0, xm));
        F3 u1 = norm3(sub3(xp, x0));
        F3 n2 = norm3(cross3(u2, u1));
        F3 o1 = norm3(sub3(u2, u1));
        F3 cc = cross3(o1, n2);
        o[3] = o1.x; o[4] = o1.y; o[5] = o1.z;
        o[6] = n2.x; o[7] = n2.y; o[8] = n2.z;
        o[9] = cc.x; o[10] = cc.y; o[11] = cc.z;
    }
    float4* Fp = (float4*)(F + (size_t)fid * 16);
    Fp[0] = make_float4(o[0], o[1], o[2], o[3]);
    Fp[1] = make_float4(o[4], o[5], o[6], o[7]);
    Fp[2] = make_float4(o[8], o[9], o[10], o[11]);
}

// ---------------- core per-edge computation ----------------
// Geometry arithmetic unchanged since R4. Final matvec uses packed-f16 dot2
// (v_dot2_f32_f16) when available: 64 instr vs 112 FMA; q/W in f16 costs
// delta_h ~3e-4 -> delta_out ~1e-5 (budget 9.4e-4).
__device__ inline void compute_edge(float4 a0, float4 a1, float4 a2,
                                    const float* __restrict__ F,
                                    const unsigned short* __restrict__ T,
                                    const f16x2 (*sW2)[4], const float (*sWq)[8],
                                    size_t bbase, int n, int j,
                                    float* __restrict__ h) {
    const float4* fjp = (const float4*)(F + (bbase + (size_t)j) * 16);
    float4 b0 = fjp[0], b1 = fjp[1], b2 = fjp[2];
    const uint4* tp = (const uint4*)(T + (size_t)(j - n + (N_ - 1)) * 16);
    uint4 t0 = tp[0], t1 = tp[1];
    float tv[16];
    unpack8(t0, tv);
    unpack8(t1, tv + 8);

    float A1x = a0.w, A1y = a1.x, A1z = a1.y;
    float A2x = a1.z, A2y = a1.w, A2z = a2.x;
    float A3x = a2.y, A3y = a2.z, A3z = a2.w;
    float B1x = b0.w, B1y = b1.x, B1z = b1.y;
    float B2x = b1.z, B2y = b1.w, B2z = b2.x;
    float B3x = b2.y, B3y = b2.z, B3z = b2.w;

    float dX0 = b0.x - a0.x, dX1 = b0.y - a0.y, dX2 = b0.z - a0.z;
    float v0 = A1x*dX0 + A1y*dX1 + A1z*dX2;
    float v1 = A2x*dX0 + A2y*dX1 + A2z*dX2;
    float v2 = A3x*dX0 + A3y*dX1 + A3z*dX2;
    float vinv = 1.0f / fmaxf(sqrtf(v0*v0 + v1*v1 + v2*v2), EPSF);
    float dU0 = v0*vinv, dU1 = v1*vinv, dU2 = v2*vinv;

    float R00 = A1x*B1x + A2x*B2x + A3x*B3x;
    float R11 = A1y*B1y + A2y*B2y + A3y*B3y;
    float R22 = A1z*B1z + A2z*B2z + A3z*B3z;
    float R21 = A1z*B1y + A2z*B2y + A3z*B3y;
    float R12 = A1y*B1z + A2y*B2z + A3y*B3z;
    float R02 = A1x*B1z + A2x*B2z + A3x*B3z;
    float R20 = A1z*B1x + A2z*B2x + A3z*B3x;
    float R10 = A1y*B1x + A2y*B2x + A3y*B3x;
    float R01 = A1x*B1y + A2x*B2y + A3x*B3y;

    float mg0 = 0.5f * sqrtf(fabsf(1.0f + R00 - R11 - R22) + EPSF);
    float mg1 = 0.5f * sqrtf(fabsf(1.0f - R00 + R11 - R22) + EPSF);
    float mg2 = 0.5f * sqrtf(fabsf(1.0f - R00 - R11 + R22) + EPSF);
    float qx = signf0(R21 - R12) * mg0;
    float qy = signf0(R02 - R20) * mg1;
    float qz = signf0(R10 - R01) * mg2;
    float qw = 0.5f * sqrtf(fmaxf(1.0f + R00 + R11 + R22, 0.0f) + EPSF);
    float qinv = 1.0f / fmaxf(sqrtf(qx*qx + qy*qy + qz*qz + qw*qw), EPSF);
    qx *= qinv; qy *= qinv; qz *= qinv; qw *= qinv;

#if __has_builtin(__builtin_amdgcn_fdot2)
    f16x2 q2[4];
    q2[0] = f16x2{(_Float16)dU0, (_Float16)dU1};
    q2[1] = f16x2{(_Float16)dU2, (_Float16)qx};
    q2[2] = f16x2{(_Float16)qy,  (_Float16)qz};
    q2[3] = f16x2{(_Float16)qw,  (_Float16)0.0f};
    #pragma unroll
    for (int o = 0; o < NEDGE; o++) {
        float a = tv[o];
        #pragma unroll
        for (int p = 0; p < 4; p++)
            a = __builtin_amdgcn_fdot2(q2[p], sW2[o][p], a, false);
        h[o] = a;
    }
#else
    float q[7] = {dU0, dU1, dU2, qx, qy, qz, qw};
    #pragma unroll
    for (int o = 0; o < NEDGE; o++) {
        float a = tv[o];
        #pragma unroll
        for (int f = 0; f < 7; f++) a = fmaf(q[f], sWq[o][f], a);
        h[o] = a;
    }
#endif
}

// ---------------- edge pass: wave = 4n x 16k, contiguous 1KB stores ----------------
// grid = 8(b) x 3(kg) x 128(nt of 64 n) = 3072 blocks. b in low 3 bits (XCD pin).
// Structure lessons: coop LDS gathers regress (R6,R12); bf16 staging regresses (R11);
// direct per-lane gathers + store-transpose only.
__launch_bounds__(256)
__global__ void edge_pass(const int* __restrict__ E, const float* __restrict__ F,
                          const unsigned short* __restrict__ T, const float* __restrict__ Wfull,
                          float* __restrict__ acc, float* __restrict__ out) {
    int bid = blockIdx.x;
    int b = bid & 7;
    int r = bid >> 3;
    int kg = r % 3;             // k-group of 16
    int nt = r / 3;             // 0..127
    int tid = threadIdx.x;
    int w = tid >> 6, l = tid & 63;
    int nn = l >> 4, kk = l & 15;
    int k = kg * 16 + kk;

    __shared__ float sT[4][64 * 17];       // wave-private transpose buffers (pad 17)
    __shared__ f16x2 sW2[NEDGE][4];        // W[:,16:23] packed f16 pairs (pad to 8)
    __shared__ float sWq[NEDGE][8];        // f32 fallback copy
    __shared__ float sAcc[4][16][NEDGE];

    if (tid < NEDGE * 8) {
        int o = tid >> 3, f = tid & 7;
        sWq[o][f] = (f < 7) ? Wfull[o * FANIN + 16 + f] : 0.0f;
    }
    if (tid < NEDGE * 4) {
        int o = tid >> 2, p = tid & 3;
        float w0 = Wfull[o * FANIN + 16 + 2 * p];
        float w1 = (2 * p + 1 < 7) ? Wfull[o * FANIN + 16 + 2 * p + 1] : 0.0f;
        sW2[o][p] = f16x2{(_Float16)w0, (_Float16)w1};
    }
    __syncthreads();

    size_t bbase = (size_t)b * N_;
    int nbase = nt * 64;
    float* myT = sT[w];

    float vsq[NEDGE];
    #pragma unroll
    for (int o = 0; o < NEDGE; o++) vsq[o] = 0.0f;

    for (int it = 0; it < 4; it++) {
        int n = nbase + it * 16 + w * 4 + nn;
        size_t node = bbase + n;
        const float4* fnp = (const float4*)(F + node * 16);
        float4 a0 = fnp[0], a1 = fnp[1], a2 = fnp[2];
        int j = E[node * K_ + k];

        float h[NEDGE];
        compute_edge(a0, a1, a2, F, T, sW2, sWq, bbase, n, j, h);

        #pragma unroll
        for (int o = 0; o < NEDGE; o++) vsq[o] = fmaf(h[o], h[o], vsq[o]);

        // wave-private LDS transpose (lockstep wave -> no __syncthreads)
        #pragma unroll
        for (int q = 0; q < 4; q++)
            *(float4*)(myT + l * 17 + q * 4) =
                make_float4(h[4*q], h[4*q+1], h[4*q+2], h[4*q+3]);

        // store: instr s writes n-row s's 16 edges = contiguous 1KB, uniform base
        #pragma unroll
        for (int s = 0; s < 4; s++) {
            int n_s = nbase + it * 16 + w * 4 + s;
            float4 v = *(float4*)(myT + ((s << 4) + (l >> 2)) * 17 + (l & 3) * 4);
            size_t outb = ((bbase + n_s) * K_ + (size_t)kg * 16) * 16;
            *(float4*)(out + outb + l * 4) = v;
        }
    }

    // ssq: reduce over the 4 n-subrows within the wave (lane bits 4-5)
    #pragma unroll
    for (int o = 0; o < NEDGE; o++) {
        float v = vsq[o];
        v += __shfl_xor(v, 16, 64);
        v += __shfl_xor(v, 32, 64);
        vsq[o] = v;
    }
    if (nn == 0 && l < 16) {
        #pragma unroll
        for (int o = 0; o < NEDGE; o++) sAcc[w][kk][o] = vsq[o];
    }
    __syncthreads();
    {
        int kk2 = tid >> 4, o = tid & 15;
        float t = sAcc[0][kk2][o] + sAcc[1][kk2][o] + sAcc[2][kk2][o] + sAcc[3][kk2][o];
        atomicAdd(&acc[((size_t)b * K_ + kg * 16 + kk2) * NEDGE + o], t);
    }
}

// ---------------- reciprocal norms ----------------
__global__ void inv_kernel(const float* __restrict__ acc, float* __restrict__ rinv) {
    int i = blockIdx.x * blockDim.x + threadIdx.x;
    if (i >= B_ * K_ * NEDGE) return;
    rinv[i] = 1.0f / fmaxf(sqrtf(acc[i]), EPSF);
}

// ---------------- rescale pass (streaming RMW; re-read is L3-resident) ----------------
// R11: bf16-staging alternative 20us slower; R10: nontemporal stores amplify
// partial-sector writes. Plain f32 RMW is best.
__launch_bounds__(256)
__global__ void scale_kernel(float* __restrict__ out, const float* __restrict__ rinv) {
    size_t idx = (size_t)blockIdx.x * blockDim.x + threadIdx.x;  // float4 index
    constexpr size_t TOTAL4 = (size_t)B_ * N_ * K_ * 4;
    if (idx >= TOTAL4) return;
    size_t e0 = idx * 4;
    unsigned int o0 = (unsigned int)(e0 & 15);
    unsigned int key = (unsigned int)(e0 >> 4);       // (b*N+n)*K + k
    unsigned int k = key % (unsigned int)K_;
    unsigned int b = key / (unsigned int)(N_ * K_);
    float4 rv = *(const float4*)(rinv + ((size_t)b * K_ + k) * 16 + o0);
    float4 vv = *reinterpret_cast<float4*>(out + e0);
    vv.x *= rv.x; vv.y *= rv.y; vv.z *= rv.z; vv.w *= rv.w;
    *reinterpret_cast<float4*>(out + e0) = vv;
}

// ---------------- launch ----------------
extern "C" void kernel_launch(void* const* d_in, const int* in_sizes, int n_in,
                              void* d_out, int out_size, void* d_ws, size_t ws_size,
                              hipStream_t stream) {
    const float* X    = (const float*)d_in[0];   // p (B,N,3)
    const int*   E    = (const int*)d_in[1];     // e_idx (B,N,K)
    // d_in[2] = mask (unused by reference)
    const float* tfrq = (const float*)d_in[3];   // (8,)
    const float* ts   = (const float*)d_in[4];   // scalar
    const float* W    = (const float*)d_in[5];   // (16,23)
    const float* bias = (const float*)d_in[6];   // (16,)
    float* out = (float*)d_out;

    float* F = (float*)d_ws;                                          // 8*8192*16 f32 = 4.19 MB
    unsigned short* T = (unsigned short*)(F + (size_t)B_ * N_ * 16);  // 16383*16 bf16 = 524 KB
    float* acc  = (float*)(T + (size_t)DRANGE * 16);                  // 6144 f32
    float* rinv = acc + B_ * K_ * NEDGE;                              // 6144 f32

    (void)hipMemsetAsync(acc, 0, (size_t)B_ * K_ * NEDGE * sizeof(float), stream);

    int prep_threads = DPAD + B_ * N_;
    prep_kernel<<<(prep_threads + 255) / 256, 256, 0, stream>>>(X, tfrq, ts, W, bias, T, F);

    int grid = 8 * 3 * 128;   // 3072 blocks, b in low 3 bits
    edge_pass<<<grid, 256, 0, stream>>>(E, F, T, W, acc, out);

    inv_kernel<<<(B_ * K_ * NEDGE + 255) / 256, 256, 0, stream>>>(acc, rinv);

    constexpr size_t TOTAL4 = (size_t)B_ * N_ * K_ * 4;
    scale_kernel<<<(TOTAL4 + 255) / 256, 256, 0, stream>>>(out, rinv);
}

// Round 15
// 135.331 us; speedup vs baseline: 1.4566x; 1.0509x over previous
//
#include <hip/hip_runtime.h>
#include <math.h>

// Problem constants (from reference)
constexpr int B_ = 8;
constexpr int N_ = 8192;
constexpr int K_ = 48;
constexpr int NFREQ = 8;    // NUM_POS/2
constexpr int NEDGE = 16;
constexpr int FANIN = 23;   // NUM_POS + 7
constexpr float EPSF = 1e-12f;
constexpr int DRANGE = 2 * N_ - 1;  // 16383 possible d = j-n values, offset N_-1
constexpr int DPAD = 16384;         // padded table slot count for fused prep kernel

typedef _Float16 f16x2 __attribute__((ext_vector_type(2)));

// ---------------- helpers ----------------
struct F3 { float x, y, z; };
__device__ inline F3 f3(float a, float b, float c) { F3 r{a,b,c}; return r; }
__device__ inline F3 sub3(F3 a, F3 b) { return f3(a.x-b.x, a.y-b.y, a.z-b.z); }
__device__ inline F3 cross3(F3 a, F3 b) {
    return f3(a.y*b.z - a.z*b.y, a.z*b.x - a.x*b.z, a.x*b.y - a.y*b.x);
}
__device__ inline F3 norm3(F3 a) {
    float n = sqrtf(a.x*a.x + a.y*a.y + a.z*a.z);
    float inv = 1.0f / fmaxf(n, EPSF);
    return f3(a.x*inv, a.y*inv, a.z*inv);
}
__device__ inline float signf0(float x) {
    return (x > 0.0f) ? 1.0f : ((x < 0.0f) ? -1.0f : 0.0f);
}
__device__ inline unsigned int bf16rne(float x) {
    unsigned int u = __float_as_uint(x);
    return (u + 0x7fffu + ((u >> 16) & 1u)) >> 16;
}
// unpack 8 bf16 (one uint4) -> 8 floats (elem 0 = low 16 bits of x)
__device__ inline void unpack8(uint4 v, float* f) {
    f[0] = __uint_as_float(v.x << 16); f[1] = __uint_as_float(v.x & 0xffff0000u);
    f[2] = __uint_as_float(v.y << 16); f[3] = __uint_as_float(v.y & 0xffff0000u);
    f[4] = __uint_as_float(v.z << 16); f[5] = __uint_as_float(v.z & 0xffff0000u);
    f[6] = __uint_as_float(v.w << 16); f[7] = __uint_as_float(v.w & 0xffff0000u);
}

// ---------------- fused prep: PE table (bf16) + per-node frames + acc zeroing ----------------
__global__ void prep_kernel(const float* __restrict__ X,
                            const float* __restrict__ tfrq, const float* __restrict__ ts,
                            const float* __restrict__ W, const float* __restrict__ bias,
                            unsigned short* __restrict__ T, float* __restrict__ F,
                            float* __restrict__ acc) {
    int idx = blockIdx.x * blockDim.x + threadIdx.x;
    if (idx < DPAD) {
        if (idx >= DRANGE) return;
        float d = (float)(idx - (N_ - 1));
        float h[NEDGE];
        #pragma unroll
        for (int o = 0; o < NEDGE; o++) h[o] = bias[o];
        float tscale = ts[0];
        for (int f = 0; f < NFREQ; f++) {
            float s, c;
            sincosf(d * (tfrq[f] * tscale), &s, &c);
            #pragma unroll
            for (int o = 0; o < NEDGE; o++)
                h[o] = fmaf(s, W[o * FANIN + f], fmaf(c, W[o * FANIN + NFREQ + f], h[o]));
        }
        uint4 r0, r1;
        r0.x = bf16rne(h[0])  | (bf16rne(h[1])  << 16);
        r0.y = bf16rne(h[2])  | (bf16rne(h[3])  << 16);
        r0.z = bf16rne(h[4])  | (bf16rne(h[5])  << 16);
        r0.w = bf16rne(h[6])  | (bf16rne(h[7])  << 16);
        r1.x = bf16rne(h[8])  | (bf16rne(h[9])  << 16);
        r1.y = bf16rne(h[10]) | (bf16rne(h[11]) << 16);
        r1.z = bf16rne(h[12]) | (bf16rne(h[13]) << 16);
        r1.w = bf16rne(h[14]) | (bf16rne(h[15]) << 16);
        uint4* Tp = (uint4*)(T + (size_t)idx * 16);
        Tp[0] = r0; Tp[1] = r1;
        return;
    }
    int fid = idx - DPAD;
    if (fid >= B_ * N_) return;
    if (fid < B_ * K_ * NEDGE) acc[fid] = 0.0f;   // fold acc memset in (6144 < B*N)
    int n = fid & (N_ - 1);
    const float* Xp = X + (size_t)fid * 3;
    float o[12];
    o[0] = Xp[0]; o[1] = Xp[1]; o[2] = Xp[2];
    #pragma unroll
    for (int i = 3; i < 12; i++) o[i] = 0.0f;
    if (n != 0 && n < N_ - 2) {
        F3 xm = f3(Xp[-3], Xp[-2], Xp[-1]);
        F3 x0 = f3(Xp[0], Xp[1], Xp[2]);
        F3 xp = f3(Xp[3], Xp[4], Xp[5]);
        F3 u2 = norm3(sub3(x0, xm));
        F3 u1 = norm3(sub3(xp, x0));
        F3 n2 = norm3(cross3(u2, u1));
        F3 o1 = norm3(sub3(u2, u1));
        F3 cc = cross3(o1, n2);
        o[3] = o1.x; o[4] = o1.y; o[5] = o1.z;
        o[6] = n2.x; o[7] = n2.y; o[8] = n2.z;
        o[9] = cc.x; o[10] = cc.y; o[11] = cc.z;
    }
    float4* Fp = (float4*)(F + (size_t)fid * 16);
    Fp[0] = make_float4(o[0], o[1], o[2], o[3]);
    Fp[1] = make_float4(o[4], o[5], o[6], o[7]);
    Fp[2] = make_float4(o[8], o[9], o[10], o[11]);
}

// ---------------- core per-edge computation ----------------
// Geometry arithmetic unchanged since R4. Final matvec uses packed-f16 dot2
// (v_dot2_f32_f16) when available (R14: -1.4%).
__device__ inline void compute_edge(float4 a0, float4 a1, float4 a2,
                                    const float* __restrict__ F,
                                    const unsigned short* __restrict__ T,
                                    const f16x2 (*sW2)[4], const float (*sWq)[8],
                                    size_t bbase, int n, int j,
                                    float* __restrict__ h) {
    const float4* fjp = (const float4*)(F + (bbase + (size_t)j) * 16);
    float4 b0 = fjp[0], b1 = fjp[1], b2 = fjp[2];
    const uint4* tp = (const uint4*)(T + (size_t)(j - n + (N_ - 1)) * 16);
    uint4 t0 = tp[0], t1 = tp[1];
    float tv[16];
    unpack8(t0, tv);
    unpack8(t1, tv + 8);

    float A1x = a0.w, A1y = a1.x, A1z = a1.y;
    float A2x = a1.z, A2y = a1.w, A2z = a2.x;
    float A3x = a2.y, A3y = a2.z, A3z = a2.w;
    float B1x = b0.w, B1y = b1.x, B1z = b1.y;
    float B2x = b1.z, B2y = b1.w, B2z = b2.x;
    float B3x = b2.y, B3y = b2.z, B3z = b2.w;

    float dX0 = b0.x - a0.x, dX1 = b0.y - a0.y, dX2 = b0.z - a0.z;
    float v0 = A1x*dX0 + A1y*dX1 + A1z*dX2;
    float v1 = A2x*dX0 + A2y*dX1 + A2z*dX2;
    float v2 = A3x*dX0 + A3y*dX1 + A3z*dX2;
    float vinv = 1.0f / fmaxf(sqrtf(v0*v0 + v1*v1 + v2*v2), EPSF);
    float dU0 = v0*vinv, dU1 = v1*vinv, dU2 = v2*vinv;

    float R00 = A1x*B1x + A2x*B2x + A3x*B3x;
    float R11 = A1y*B1y + A2y*B2y + A3y*B3y;
    float R22 = A1z*B1z + A2z*B2z + A3z*B3z;
    float R21 = A1z*B1y + A2z*B2y + A3z*B3y;
    float R12 = A1y*B1z + A2y*B2z + A3y*B3z;
    float R02 = A1x*B1z + A2x*B2z + A3x*B3z;
    float R20 = A1z*B1x + A2z*B2x + A3z*B3x;
    float R10 = A1y*B1x + A2y*B2x + A3y*B3x;
    float R01 = A1x*B1y + A2x*B2y + A3x*B3y;

    float mg0 = 0.5f * sqrtf(fabsf(1.0f + R00 - R11 - R22) + EPSF);
    float mg1 = 0.5f * sqrtf(fabsf(1.0f - R00 + R11 - R22) + EPSF);
    float mg2 = 0.5f * sqrtf(fabsf(1.0f - R00 - R11 + R22) + EPSF);
    float qx = signf0(R21 - R12) * mg0;
    float qy = signf0(R02 - R20) * mg1;
    float qz = signf0(R10 - R01) * mg2;
    float qw = 0.5f * sqrtf(fmaxf(1.0f + R00 + R11 + R22, 0.0f) + EPSF);
    float qinv = 1.0f / fmaxf(sqrtf(qx*qx + qy*qy + qz*qz + qw*qw), EPSF);
    qx *= qinv; qy *= qinv; qz *= qinv; qw *= qinv;

#if __has_builtin(__builtin_amdgcn_fdot2)
    f16x2 q2[4];
    q2[0] = f16x2{(_Float16)dU0, (_Float16)dU1};
    q2[1] = f16x2{(_Float16)dU2, (_Float16)qx};
    q2[2] = f16x2{(_Float16)qy,  (_Float16)qz};
    q2[3] = f16x2{(_Float16)qw,  (_Float16)0.0f};
    #pragma unroll
    for (int o = 0; o < NEDGE; o++) {
        float a = tv[o];
        #pragma unroll
        for (int p = 0; p < 4; p++)
            a = __builtin_amdgcn_fdot2(q2[p], sW2[o][p], a, false);
        h[o] = a;
    }
#else
    float q[7] = {dU0, dU1, dU2, qx, qy, qz, qw};
    #pragma unroll
    for (int o = 0; o < NEDGE; o++) {
        float a = tv[o];
        #pragma unroll
        for (int f = 0; f < 7; f++) a = fmaf(q[f], sWq[o][f], a);
        h[o] = a;
    }
#endif
}

// ---------------- edge pass: wave = 4n x 16k, contiguous 1KB stores ----------------
// grid = 8(b) x 3(kg) x 128(nt of 64 n) = 3072 blocks. b in low 3 bits (XCD pin).
// Structure lessons: coop LDS gathers regress (R6,R12); bf16 staging regresses (R11);
// direct per-lane gathers + store-transpose only.
__launch_bounds__(256)
__global__ void edge_pass(const int* __restrict__ E, const float* __restrict__ F,
                          const unsigned short* __restrict__ T, const float* __restrict__ Wfull,
                          float* __restrict__ acc, float* __restrict__ out) {
    int bid = blockIdx.x;
    int b = bid & 7;
    int r = bid >> 3;
    int kg = r % 3;             // k-group of 16
    int nt = r / 3;             // 0..127
    int tid = threadIdx.x;
    int w = tid >> 6, l = tid & 63;
    int nn = l >> 4, kk = l & 15;
    int k = kg * 16 + kk;

    __shared__ float sT[4][64 * 17];       // wave-private transpose buffers (pad 17)
    __shared__ f16x2 sW2[NEDGE][4];        // W[:,16:23] packed f16 pairs
    __shared__ float sWq[NEDGE][8];        // f32 fallback copy
    __shared__ float sAcc[4][16][NEDGE];

    if (tid < NEDGE * 8) {
        int o = tid >> 3, f = tid & 7;
        sWq[o][f] = (f < 7) ? Wfull[o * FANIN + 16 + f] : 0.0f;
    }
    if (tid < NEDGE * 4) {
        int o = tid >> 2, p = tid & 3;
        float w0 = Wfull[o * FANIN + 16 + 2 * p];
        float w1 = (2 * p + 1 < 7) ? Wfull[o * FANIN + 16 + 2 * p + 1] : 0.0f;
        sW2[o][p] = f16x2{(_Float16)w0, (_Float16)w1};
    }
    __syncthreads();

    size_t bbase = (size_t)b * N_;
    int nbase = nt * 64;
    float* myT = sT[w];

    float vsq[NEDGE];
    #pragma unroll
    for (int o = 0; o < NEDGE; o++) vsq[o] = 0.0f;

    for (int it = 0; it < 4; it++) {
        int n = nbase + it * 16 + w * 4 + nn;
        size_t node = bbase + n;
        const float4* fnp = (const float4*)(F + node * 16);
        float4 a0 = fnp[0], a1 = fnp[1], a2 = fnp[2];
        int j = E[node * K_ + k];

        float h[NEDGE];
        compute_edge(a0, a1, a2, F, T, sW2, sWq, bbase, n, j, h);

        #pragma unroll
        for (int o = 0; o < NEDGE; o++) vsq[o] = fmaf(h[o], h[o], vsq[o]);

        // wave-private LDS transpose (lockstep wave -> no __syncthreads)
        #pragma unroll
        for (int q = 0; q < 4; q++)
            *(float4*)(myT + l * 17 + q * 4) =
                make_float4(h[4*q], h[4*q+1], h[4*q+2], h[4*q+3]);

        // store: instr s writes n-row s's 16 edges = contiguous 1KB, uniform base
        #pragma unroll
        for (int s = 0; s < 4; s++) {
            int n_s = nbase + it * 16 + w * 4 + s;
            float4 v = *(float4*)(myT + ((s << 4) + (l >> 2)) * 17 + (l & 3) * 4);
            size_t outb = ((bbase + n_s) * K_ + (size_t)kg * 16) * 16;
            *(float4*)(out + outb + l * 4) = v;
        }
    }

    // ssq: reduce over the 4 n-subrows within the wave (lane bits 4-5)
    #pragma unroll
    for (int o = 0; o < NEDGE; o++) {
        float v = vsq[o];
        v += __shfl_xor(v, 16, 64);
        v += __shfl_xor(v, 32, 64);
        vsq[o] = v;
    }
    if (nn == 0 && l < 16) {
        #pragma unroll
        for (int o = 0; o < NEDGE; o++) sAcc[w][kk][o] = vsq[o];
    }
    __syncthreads();
    {
        int kk2 = tid >> 4, o = tid & 15;
        float t = sAcc[0][kk2][o] + sAcc[1][kk2][o] + sAcc[2][kk2][o] + sAcc[3][kk2][o];
        atomicAdd(&acc[((size_t)b * K_ + kg * 16 + kk2) * NEDGE + o], t);
    }
}

// ---------------- rescale pass (streaming RMW; inv fused in — VALUBusy was 2%) ----------------
// R11: bf16-staging alternative 20us slower; R10: nontemporal stores amplify
// partial-sector writes. Plain f32 RMW; rinv computed inline from acc (L2-resident,
// arithmetic identical to the old inv_kernel).
__launch_bounds__(256)
__global__ void scale_kernel(float* __restrict__ out, const float* __restrict__ acc) {
    size_t idx = (size_t)blockIdx.x * blockDim.x + threadIdx.x;  // float4 index
    constexpr size_t TOTAL4 = (size_t)B_ * N_ * K_ * 4;
    if (idx >= TOTAL4) return;
    size_t e0 = idx * 4;
    unsigned int o0 = (unsigned int)(e0 & 15);
    unsigned int key = (unsigned int)(e0 >> 4);       // (b*N+n)*K + k
    unsigned int k = key % (unsigned int)K_;
    unsigned int b = key / (unsigned int)(N_ * K_);
    float4 av = *(const float4*)(acc + ((size_t)b * K_ + k) * 16 + o0);
    float4 rv;
    rv.x = 1.0f / fmaxf(sqrtf(av.x), EPSF);
    rv.y = 1.0f / fmaxf(sqrtf(av.y), EPSF);
    rv.z = 1.0f / fmaxf(sqrtf(av.z), EPSF);
    rv.w = 1.0f / fmaxf(sqrtf(av.w), EPSF);
    float4 vv = *reinterpret_cast<float4*>(out + e0);
    vv.x *= rv.x; vv.y *= rv.y; vv.z *= rv.z; vv.w *= rv.w;
    *reinterpret_cast<float4*>(out + e0) = vv;
}

// ---------------- launch ----------------
extern "C" void kernel_launch(void* const* d_in, const int* in_sizes, int n_in,
                              void* d_out, int out_size, void* d_ws, size_t ws_size,
                              hipStream_t stream) {
    const float* X    = (const float*)d_in[0];   // p (B,N,3)
    const int*   E    = (const int*)d_in[1];     // e_idx (B,N,K)
    // d_in[2] = mask (unused by reference)
    const float* tfrq = (const float*)d_in[3];   // (8,)
    const float* ts   = (const float*)d_in[4];   // scalar
    const float* W    = (const float*)d_in[5];   // (16,23)
    const float* bias = (const float*)d_in[6];   // (16,)
    float* out = (float*)d_out;

    float* F = (float*)d_ws;                                          // 8*8192*16 f32 = 4.19 MB
    unsigned short* T = (unsigned short*)(F + (size_t)B_ * N_ * 16);  // 16383*16 bf16 = 524 KB
    float* acc  = (float*)(T + (size_t)DRANGE * 16);                  // 6144 f32

    int prep_threads = DPAD + B_ * N_;
    prep_kernel<<<(prep_threads + 255) / 256, 256, 0, stream>>>(X, tfrq, ts, W, bias, T, F, acc);

    int grid = 8 * 3 * 128;   // 3072 blocks, b in low 3 bits
    edge_pass<<<grid, 256, 0, stream>>>(E, F, T, W, acc, out);

    constexpr size_t TOTAL4 = (size_t)B_ * N_ * K_ * 4;
    scale_kernel<<<(TOTAL4 + 255) / 256, 256, 0, stream>>>(out, acc);
}